// Round 6
// baseline (746.949 us; speedup 1.0000x reference)
//
#include <hip/hip_runtime.h>
#include <hip/hip_bf16.h>

#define GLOBAL_AS __attribute__((address_space(1)))
#define LDS_AS    __attribute__((address_space(3)))

typedef __bf16 bf16x8 __attribute__((ext_vector_type(8)));
typedef __bf16 bf16x4 __attribute__((ext_vector_type(4)));
typedef float  f32x4v __attribute__((ext_vector_type(4)));

// ---------------- K1: RMSNorm -> t_f32, t_bf16 ----------------
__global__ __launch_bounds__(256) void k_rmsnorm(const float* __restrict__ x,
        const float* __restrict__ sc, float* __restrict__ t32,
        __bf16* __restrict__ t16)
{
    const int t = blockIdx.x, tid = threadIdx.x;
    const float4 v = ((const float4*)(x + (size_t)t * 1024))[tid];
    float ss = v.x*v.x + v.y*v.y + v.z*v.z + v.w*v.w;
    #pragma unroll
    for (int s = 32; s; s >>= 1) ss += __shfl_xor(ss, s, 64);
    __shared__ float red[4];
    if ((tid & 63) == 0) red[tid >> 6] = ss;
    __syncthreads();
    const float tot = red[0] + red[1] + red[2] + red[3];
    const float rs = rsqrtf(tot * (1.0f / 1024.0f) + 1e-5f);
    const float4 s4 = ((const float4*)sc)[tid];
    float4 o;
    o.x = v.x * rs * s4.x; o.y = v.y * rs * s4.y;
    o.z = v.z * rs * s4.z; o.w = v.w * rs * s4.w;
    ((float4*)(t32 + (size_t)t * 1024))[tid] = o;
    bf16x4 p;
    p[0] = (__bf16)o.x; p[1] = (__bf16)o.y; p[2] = (__bf16)o.z; p[3] = (__bf16)o.w;
    ((bf16x4*)(t16 + (size_t)t * 1024))[tid] = p;
}

// ---------------- K2: gate logits (fp32) + top4 + softmax ----------------
__global__ __launch_bounds__(256) void k_gate(const float* __restrict__ t32,
        const float* __restrict__ gw, const float* __restrict__ gb,
        int* __restrict__ idx, float* __restrict__ ew)
{
    const int t = blockIdx.x, tid = threadIdx.x;
    __shared__ float4 tl[256];
    __shared__ float part[4][64];
    tl[tid] = ((const float4*)(t32 + (size_t)t * 1024))[tid];
    __syncthreads();
    const int q = tid >> 6, e = tid & 63;
    const float4* w4 = (const float4*)(gw + (size_t)e * 1024 + q * 256);
    const float4* a4 = &tl[q * 64];
    float acc = 0.0f;
    #pragma unroll 8
    for (int i = 0; i < 64; ++i) {
        const float4 a = a4[i], b = w4[i];
        acc += a.x*b.x + a.y*b.y + a.z*b.z + a.w*b.w;
    }
    part[q][e] = acc;
    __syncthreads();
    if (tid < 64) {
        float cur = part[0][tid] + part[1][tid] + part[2][tid] + part[3][tid] + gb[tid];
        float vals[4]; int ids[4];
        #pragma unroll
        for (int k = 0; k < 4; ++k) {
            float m = cur;
            #pragma unroll
            for (int s = 32; s; s >>= 1) m = fmaxf(m, __shfl_xor(m, s, 64));
            const unsigned long long b = __ballot(cur == m);
            const int bi = __ffsll(b) - 1;
            vals[k] = m; ids[k] = bi;
            if (tid == bi) cur = -3.0e38f;
        }
        float ex[4], s = 0.0f;
        #pragma unroll
        for (int k = 0; k < 4; ++k) { ex[k] = expf(vals[k] - vals[0]); s += ex[k]; }
        if (tid < 4) { idx[t * 4 + tid] = ids[tid]; ew[t * 4 + tid] = ex[tid] / s; }
    }
}

// ---------------- K3: bucket (token,expert) pairs by expert ----------------
__global__ __launch_bounds__(256) void k_bucket(const int* __restrict__ idx,
        const float* __restrict__ ewv, int* __restrict__ eoff,
        int* __restrict__ slot_token, float* __restrict__ slot_ew,
        int* __restrict__ token_slots)
{
    __shared__ int cnt[64], cur[64];
    const int tid = threadIdx.x;
    if (tid < 64) cnt[tid] = 0;
    __syncthreads();
    for (int p = tid; p < 4096; p += 256) atomicAdd(&cnt[idx[p]], 1);
    __syncthreads();
    if (tid == 0) {
        int s = 0;
        for (int e = 0; e < 64; ++e) { eoff[e] = s; cur[e] = s; s += cnt[e]; }
        eoff[64] = s;
    }
    __syncthreads();
    for (int p = tid; p < 4096; p += 256) {
        const int e = idx[p];
        const int s = atomicAdd(&cur[e], 1);
        slot_token[s] = p >> 2;
        slot_ew[s] = ewv[p];
        token_slots[p] = s;
    }
}

// ---------------- K4/K5: grouped GEMM (round-3 structure) + REP loop ----------------
// REPS>1 repeats the whole computation idempotently so the dispatch is long
// enough to surface in rocprof top-5 (harness poison fills occlude it).
template<int MODE>
__global__ __launch_bounds__(256, 2) void k_gemm(
        const float* __restrict__ W, const float* __restrict__ Bias,
        const __bf16* __restrict__ A,
        const int* __restrict__ eoff, const int* __restrict__ slot_token,
        const float* __restrict__ slot_ew,
        __bf16* __restrict__ act_out, __bf16* __restrict__ o_buf, int reps)
{
    constexpr int NPE = (MODE == 0) ? 2048 : 1024;
    const int d  = blockIdx.y * gridDim.x + blockIdx.x;
    const int e  = (d & 7) * 8 + ((d >> 3) & 7);
    const int nt = d >> 6;
    const int ph = (d * 7) & 15;
    const int off = eoff[e];
    const int count = eoff[e + 1] - off;
    if (count == 0) return;
    const int tid = threadIdx.x;
    const int wv = tid >> 6, l = tid & 63;
    const int wm = wv >> 1, wn = wv & 1;

    __shared__ __attribute__((aligned(16))) unsigned char lds[2][32768];

    const float* Wb = W + (size_t)e * NPE * 1024 + (size_t)nt * 128 * 1024;

#define KCOL(kt) ((ph + (kt)) & 15)

#define DMA_A(sbuf, kt) do {                                                   \
    const int kc_ = KCOL(kt);                                                  \
    _Pragma("unroll")                                                          \
    for (int i_ = 0; i_ < 4; ++i_)                                             \
        __builtin_amdgcn_global_load_lds(                                      \
            (const GLOBAL_AS void*)(asrc[i_] + kc_ * 128),                     \
            (LDS_AS void*)&lds[sbuf][(wv * 4 + i_) * 1024], 16, 0, 0);         \
    } while (0)

#define LOAD_B(dst, kt) do {                                                   \
    const int kc_ = KCOL(kt);                                                  \
    _Pragma("unroll")                                                          \
    for (int it_ = 0; it_ < 8; ++it_) {                                        \
        const int fid_ = it_ * 256 + tid;                                      \
        dst[it_] = *(const float4*)(Wb + (size_t)(fid_ >> 4) * 1024            \
                                    + kc_ * 64 + (fid_ & 15) * 4);             \
    } } while (0)

#define WRITE_B(src, sbuf) do {                                                \
    _Pragma("unroll")                                                          \
    for (int it_ = 0; it_ < 8; ++it_) {                                        \
        const int fid_ = it_ * 256 + tid;                                      \
        const int row_ = fid_ >> 4, c4_ = fid_ & 15;                           \
        bf16x4 p_;                                                             \
        p_[0] = (__bf16)src[it_].x; p_[1] = (__bf16)src[it_].y;                \
        p_[2] = (__bf16)src[it_].z; p_[3] = (__bf16)src[it_].w;                \
        *(bf16x4*)(&lds[sbuf][16384 + row_ * 128 +                             \
                   ((c4_ * 8) ^ ((row_ & 7) << 4))]) = p_;                     \
    } } while (0)

#define COMPUTE(cbuf) do {                                                     \
    _Pragma("unroll")                                                          \
    for (int kk_ = 0; kk_ < 2; ++kk_) {                                        \
        bf16x8 af_[4], bf_[4];                                                 \
        _Pragma("unroll")                                                      \
        for (int m_ = 0; m_ < 4; ++m_) {                                       \
            const int row_ = wm * 64 + m_ * 16 + (l & 15);                     \
            af_[m_] = *(const bf16x8*)(&lds[cbuf][row_ * 128 +                 \
                      ((kk_ * 64 + ((l >> 4) * 16)) ^ ((row_ & 7) << 4))]);    \
        }                                                                      \
        _Pragma("unroll")                                                      \
        for (int n_ = 0; n_ < 4; ++n_) {                                       \
            const int row_ = wn * 64 + n_ * 16 + (l & 15);                     \
            bf_[n_] = *(const bf16x8*)(&lds[cbuf][16384 + row_ * 128 +         \
                      ((kk_ * 64 + ((l >> 4) * 16)) ^ ((row_ & 7) << 4))]);    \
        }                                                                      \
        _Pragma("unroll")                                                      \
        for (int m_ = 0; m_ < 4; ++m_)                                         \
            _Pragma("unroll")                                                  \
            for (int n_ = 0; n_ < 4; ++n_)                                     \
                acc[m_][n_] = __builtin_amdgcn_mfma_f32_16x16x32_bf16(         \
                                  af_[m_], bf_[n_], acc[m_][n_], 0, 0, 0);     \
    } } while (0)

    #pragma unroll 1
    for (int rep = 0; rep < reps; ++rep) {
    for (int mt = 0; mt * 128 < count; ++mt) {
        const unsigned char* asrc[4];
        #pragma unroll
        for (int i = 0; i < 4; ++i) {
            const int chunk = wv * 4 + i;
            const int row = chunk * 8 + (l >> 3);
            const int colbyte = ((l & 7) ^ (l >> 3)) << 4;
            int arow;
            if (MODE == 0) {
                int slot = off + mt * 128 + row;
                const int smax = off + count - 1;
                if (slot > smax) slot = smax;
                arow = slot_token[slot];
            } else {
                arow = off + mt * 128 + row;
            }
            asrc[i] = (const unsigned char*)A + (size_t)arow * 2048 + colbyte;
        }

        f32x4v acc[4][4];
        #pragma unroll
        for (int m = 0; m < 4; ++m)
            #pragma unroll
            for (int n = 0; n < 4; ++n)
                acc[m][n] = f32x4v{0.f, 0.f, 0.f, 0.f};

        float4 bvA[8], bvB[8];

        // ---- prologue ----
        DMA_A(0, 0);
        __builtin_amdgcn_sched_barrier(0);
        LOAD_B(bvA, 0);
        WRITE_B(bvA, 0);
        __builtin_amdgcn_sched_barrier(0);
        LOAD_B(bvA, 1);
        asm volatile("s_waitcnt lgkmcnt(0)" ::: "memory");
        __builtin_amdgcn_sched_barrier(0);
        __builtin_amdgcn_s_barrier();

        #pragma unroll 1
        for (int p = 0; p < 7; ++p) {
            const int kt0 = 2 * p, kt1 = 2 * p + 1;
            DMA_A(1, kt0 + 1);
            __builtin_amdgcn_sched_barrier(0);
            LOAD_B(bvB, kt0 + 2);
            __builtin_amdgcn_sched_barrier(0);
            COMPUTE(0);
            WRITE_B(bvA, 1);
            asm volatile("s_waitcnt vmcnt(8) lgkmcnt(0)" ::: "memory");
            __builtin_amdgcn_sched_barrier(0);
            __builtin_amdgcn_s_barrier();
            DMA_A(0, kt1 + 1);
            __builtin_amdgcn_sched_barrier(0);
            LOAD_B(bvA, kt1 + 2);
            __builtin_amdgcn_sched_barrier(0);
            COMPUTE(1);
            WRITE_B(bvB, 0);
            asm volatile("s_waitcnt vmcnt(8) lgkmcnt(0)" ::: "memory");
            __builtin_amdgcn_sched_barrier(0);
            __builtin_amdgcn_s_barrier();
        }

        // ---- tail: kt=14,15 ----
        DMA_A(1, 15);
        __builtin_amdgcn_sched_barrier(0);
        COMPUTE(0);
        WRITE_B(bvA, 1);
        asm volatile("s_waitcnt vmcnt(0) lgkmcnt(0)" ::: "memory");
        __builtin_amdgcn_sched_barrier(0);
        __builtin_amdgcn_s_barrier();
        COMPUTE(1);

        // ---- epilogue ----
        #pragma unroll
        for (int m = 0; m < 4; ++m) {
            #pragma unroll
            for (int n = 0; n < 4; ++n) {
                #pragma unroll
                for (int j = 0; j < 4; ++j) {
                    const int row  = wm * 64 + m * 16 + (l >> 4) * 4 + j;
                    const int coll = wn * 64 + n * 16 + (l & 15);
                    const int gn = nt * 128 + coll;
                    const int gm = mt * 128 + row;
                    if (MODE == 0) {
                        float v = acc[m][n][j] + Bias[(size_t)e * NPE + gn];
                        const float partner = __shfl_xor(v, 1, 64);
                        if (!(l & 1) && gm < count) {
                            const float g  = fminf(v, 7.0f);
                            const float lv = fminf(fmaxf(partner, -7.0f), 7.0f);
                            const float r  = g / (1.0f + expf(-1.702f * g)) * (lv + 1.0f);
                            act_out[(size_t)(off + gm) * 1024 + (gn >> 1)] = (__bf16)r;
                        }
                    } else {
                        if (gm < count) {
                            const int slot = off + gm;
                            const float v = acc[m][n][j] + Bias[(size_t)e * NPE + gn];
                            o_buf[(size_t)slot * 1024 + gn] = (__bf16)(v * slot_ew[slot]);
                        }
                    }
                }
            }
        }
        // ensure LDS reuse across mt/rep iterations is ordered
        __builtin_amdgcn_s_barrier();
    }
    }
#undef DMA_A
#undef LOAD_B
#undef WRITE_B
#undef COMPUTE
#undef KCOL
}

// ---------------- K6: out = x + sum_k o_buf[slot(t,k)] (obuf bf16) ----------------
__global__ __launch_bounds__(256) void k_combine(const float* __restrict__ x,
        const __bf16* __restrict__ o_buf, const int* __restrict__ tslot,
        float* __restrict__ out)
{
    const int t = blockIdx.x, tid = threadIdx.x;
    float4 r = ((const float4*)(x + (size_t)t * 1024))[tid];
    #pragma unroll
    for (int k = 0; k < 4; ++k) {
        const int s = tslot[t * 4 + k];
        const bf16x4 o = ((const bf16x4*)(o_buf + (size_t)s * 1024))[tid];
        r.x += (float)o[0]; r.y += (float)o[1];
        r.z += (float)o[2]; r.w += (float)o[3];
    }
    ((float4*)(out + (size_t)t * 1024))[tid] = r;
}

extern "C" void kernel_launch(void* const* d_in, const int* in_sizes, int n_in,
                              void* d_out, int out_size, void* d_ws, size_t ws_size,
                              hipStream_t stream)
{
    const float* x   = (const float*)d_in[0];
    const float* nsc = (const float*)d_in[1];
    const float* gw  = (const float*)d_in[2];
    const float* gb  = (const float*)d_in[3];
    const float* w1  = (const float*)d_in[4];
    const float* b1  = (const float*)d_in[5];
    const float* w2  = (const float*)d_in[6];
    const float* b2  = (const float*)d_in[7];
    float* out = (float*)d_out;
    (void)in_sizes; (void)n_in; (void)out_size; (void)ws_size;

    char* ws = (char*)d_ws;
    float*  t32   = (float*)(ws);                                  // 4 MiB
    __bf16* t16   = (__bf16*)(ws + (4u  << 20));                   // 2 MiB
    __bf16* act   = (__bf16*)(ws + (6u  << 20));                   // 8.4 MiB
    __bf16* obuf  = (__bf16*)(ws + (16u << 20));                   // 8.4 MiB
    int*    idx   = (int*)  (ws + (34u << 20));
    float*  ew    = (float*)(ws + (34u << 20) + 1 * 65536);
    int*    stok  = (int*)  (ws + (34u << 20) + 2 * 65536);
    float*  sew   = (float*)(ws + (34u << 20) + 3 * 65536);
    int*    tslot = (int*)  (ws + (34u << 20) + 4 * 65536);
    int*    eoff  = (int*)  (ws + (34u << 20) + 5 * 65536);

    k_rmsnorm<<<1024, 256, 0, stream>>>(x, nsc, t32, t16);
    k_gate   <<<1024, 256, 0, stream>>>(t32, gw, gb, idx, ew);
    k_bucket <<<   1, 256, 0, stream>>>(idx, ew, eoff, stok, sew, tslot);
    // INSTRUMENTATION ROUND: reps=3 / reps=4 lengthen the GEMM dispatches past
    // the harness poison fills (~330 us) so they surface in rocprof top-5 with
    // full counters. Idempotent; removed next round.
    k_gemm<0><<<dim3(16, 64), 256, 0, stream>>>(w1, b1, t16, eoff, stok, sew, act, nullptr, 3);
    k_gemm<1><<<dim3( 8, 64), 256, 0, stream>>>(w2, b2, act, eoff, stok, sew, nullptr, obuf, 4);
    k_combine<<<1024, 256, 0, stream>>>(x, obuf, tslot, out);
}

// Round 7
// 288.805 us; speedup vs baseline: 2.5863x; 2.5863x over previous
//
#include <hip/hip_runtime.h>
#include <hip/hip_bf16.h>

#define GLOBAL_AS __attribute__((address_space(1)))
#define LDS_AS    __attribute__((address_space(3)))

typedef __bf16 bf16x8 __attribute__((ext_vector_type(8)));
typedef __bf16 bf16x4 __attribute__((ext_vector_type(4)));
typedef float  f32x4v __attribute__((ext_vector_type(4)));

// ---------------- K1: RMSNorm -> t_f32, t_bf16 ----------------
__global__ __launch_bounds__(256) void k_rmsnorm(const float* __restrict__ x,
        const float* __restrict__ sc, float* __restrict__ t32,
        __bf16* __restrict__ t16)
{
    const int t = blockIdx.x, tid = threadIdx.x;
    const float4 v = ((const float4*)(x + (size_t)t * 1024))[tid];
    float ss = v.x*v.x + v.y*v.y + v.z*v.z + v.w*v.w;
    #pragma unroll
    for (int s = 32; s; s >>= 1) ss += __shfl_xor(ss, s, 64);
    __shared__ float red[4];
    if ((tid & 63) == 0) red[tid >> 6] = ss;
    __syncthreads();
    const float tot = red[0] + red[1] + red[2] + red[3];
    const float rs = rsqrtf(tot * (1.0f / 1024.0f) + 1e-5f);
    const float4 s4 = ((const float4*)sc)[tid];
    float4 o;
    o.x = v.x * rs * s4.x; o.y = v.y * rs * s4.y;
    o.z = v.z * rs * s4.z; o.w = v.w * rs * s4.w;
    ((float4*)(t32 + (size_t)t * 1024))[tid] = o;
    bf16x4 p;
    p[0] = (__bf16)o.x; p[1] = (__bf16)o.y; p[2] = (__bf16)o.z; p[3] = (__bf16)o.w;
    ((bf16x4*)(t16 + (size_t)t * 1024))[tid] = p;
}

// ---------------- K2: gate logits (fp32) + top4 + softmax ----------------
__global__ __launch_bounds__(256) void k_gate(const float* __restrict__ t32,
        const float* __restrict__ gw, const float* __restrict__ gb,
        int* __restrict__ idx, float* __restrict__ ew)
{
    const int t = blockIdx.x, tid = threadIdx.x;
    __shared__ float4 tl[256];
    __shared__ float part[4][64];
    tl[tid] = ((const float4*)(t32 + (size_t)t * 1024))[tid];
    __syncthreads();
    const int q = tid >> 6, e = tid & 63;
    const float4* w4 = (const float4*)(gw + (size_t)e * 1024 + q * 256);
    const float4* a4 = &tl[q * 64];
    float acc = 0.0f;
    #pragma unroll 8
    for (int i = 0; i < 64; ++i) {
        const float4 a = a4[i], b = w4[i];
        acc += a.x*b.x + a.y*b.y + a.z*b.z + a.w*b.w;
    }
    part[q][e] = acc;
    __syncthreads();
    if (tid < 64) {
        float cur = part[0][tid] + part[1][tid] + part[2][tid] + part[3][tid] + gb[tid];
        float vals[4]; int ids[4];
        #pragma unroll
        for (int k = 0; k < 4; ++k) {
            float m = cur;
            #pragma unroll
            for (int s = 32; s; s >>= 1) m = fmaxf(m, __shfl_xor(m, s, 64));
            const unsigned long long b = __ballot(cur == m);
            const int bi = __ffsll(b) - 1;
            vals[k] = m; ids[k] = bi;
            if (tid == bi) cur = -3.0e38f;
        }
        float ex[4], s = 0.0f;
        #pragma unroll
        for (int k = 0; k < 4; ++k) { ex[k] = expf(vals[k] - vals[0]); s += ex[k]; }
        if (tid < 4) { idx[t * 4 + tid] = ids[tid]; ew[t * 4 + tid] = ex[tid] / s; }
    }
}

// ---------------- K3: bucket (token,expert) pairs by expert ----------------
__global__ __launch_bounds__(256) void k_bucket(const int* __restrict__ idx,
        const float* __restrict__ ewv, int* __restrict__ eoff,
        int* __restrict__ slot_token, float* __restrict__ slot_ew,
        int* __restrict__ token_slots)
{
    __shared__ int cnt[64], cur[64];
    const int tid = threadIdx.x;
    if (tid < 64) cnt[tid] = 0;
    __syncthreads();
    for (int p = tid; p < 4096; p += 256) atomicAdd(&cnt[idx[p]], 1);
    __syncthreads();
    if (tid == 0) {
        int s = 0;
        for (int e = 0; e < 64; ++e) { eoff[e] = s; cur[e] = s; s += cnt[e]; }
        eoff[64] = s;
    }
    __syncthreads();
    for (int p = tid; p < 4096; p += 256) {
        const int e = idx[p];
        const int s = atomicAdd(&cur[e], 1);
        slot_token[s] = p >> 2;
        slot_ew[s] = ewv[p];
        token_slots[p] = s;
    }
}

// ---------------- K4/K5: grouped GEMM, BM=128 BN=64 BK=64, 4 blocks/CU ----------------
// LDS 40KB: A double-buffered (2x16KB, global_load_lds, pre-swizzled src),
// B single-buffered bf16 (8KB) with 2-deep register prefetch as 2nd buffer.
// Per step: issue next {A-DMA, B-loads} FIRST, vmcnt(8) retires current step's
// 8 ops while next 8 stay in flight across both barriers.
template<int MODE>
__global__ __launch_bounds__(256, 4) void k_gemm(
        const float* __restrict__ W, const float* __restrict__ Bias,
        const __bf16* __restrict__ A,
        const int* __restrict__ eoff, const int* __restrict__ slot_token,
        const float* __restrict__ slot_ew,
        __bf16* __restrict__ act_out, __bf16* __restrict__ o_buf)
{
    constexpr int NPE = (MODE == 0) ? 2048 : 1024;
    const int e  = blockIdx.y;
    const int nt = blockIdx.x;                 // 64-col panel index
    const int off = eoff[e];
    const int count = eoff[e + 1] - off;
    if (count == 0) return;
    const int tid = threadIdx.x;
    const int wv = tid >> 6, l = tid & 63;
    const int wm = wv >> 1, wn = wv & 1;       // 2 M-halves x 2 N-halves

    __shared__ __attribute__((aligned(16))) unsigned char lds_a[2][16384];
    __shared__ __attribute__((aligned(16))) unsigned char lds_b[8192];

    const float* Wb = W + (size_t)e * NPE * 1024 + (size_t)nt * 64 * 1024;

#define DMA_A(sbuf, kt) do {                                                   \
    _Pragma("unroll")                                                          \
    for (int i_ = 0; i_ < 4; ++i_)                                             \
        __builtin_amdgcn_global_load_lds(                                      \
            (const GLOBAL_AS void*)(asrc[i_] + (kt) * 128),                    \
            (LDS_AS void*)&lds_a[sbuf][(wv * 4 + i_) * 1024], 16, 0, 0);       \
    } while (0)

#define LOAD_B(dst, kt) do {                                                   \
    _Pragma("unroll")                                                          \
    for (int it_ = 0; it_ < 4; ++it_) {                                        \
        const int fid_ = it_ * 256 + tid;                                      \
        dst[it_] = *(const float4*)(Wb + (size_t)(fid_ >> 4) * 1024            \
                                    + (kt) * 64 + (fid_ & 15) * 4);            \
    } } while (0)

#define WRITE_B(src) do {                                                      \
    _Pragma("unroll")                                                          \
    for (int it_ = 0; it_ < 4; ++it_) {                                        \
        const int fid_ = it_ * 256 + tid;                                      \
        const int row_ = fid_ >> 4, c4_ = fid_ & 15;                           \
        bf16x4 p_;                                                             \
        p_[0] = (__bf16)src[it_].x; p_[1] = (__bf16)src[it_].y;                \
        p_[2] = (__bf16)src[it_].z; p_[3] = (__bf16)src[it_].w;                \
        *(bf16x4*)(&lds_b[row_ * 128 +                                         \
                   ((c4_ * 8) ^ ((row_ & 7) << 4))]) = p_;                     \
    } } while (0)

#define COMPUTE(cbuf) do {                                                     \
    _Pragma("unroll")                                                          \
    for (int kk_ = 0; kk_ < 2; ++kk_) {                                        \
        bf16x8 af_[4], bf_[2];                                                 \
        _Pragma("unroll")                                                      \
        for (int m_ = 0; m_ < 4; ++m_) {                                       \
            const int row_ = wm * 64 + m_ * 16 + (l & 15);                     \
            af_[m_] = *(const bf16x8*)(&lds_a[cbuf][row_ * 128 +               \
                      ((kk_ * 64 + ((l >> 4) * 16)) ^ ((row_ & 7) << 4))]);    \
        }                                                                      \
        _Pragma("unroll")                                                      \
        for (int n_ = 0; n_ < 2; ++n_) {                                       \
            const int row_ = wn * 32 + n_ * 16 + (l & 15);                     \
            bf_[n_] = *(const bf16x8*)(&lds_b[row_ * 128 +                     \
                      ((kk_ * 64 + ((l >> 4) * 16)) ^ ((row_ & 7) << 4))]);    \
        }                                                                      \
        _Pragma("unroll")                                                      \
        for (int m_ = 0; m_ < 4; ++m_)                                         \
            _Pragma("unroll")                                                  \
            for (int n_ = 0; n_ < 2; ++n_)                                     \
                acc[m_][n_] = __builtin_amdgcn_mfma_f32_16x16x32_bf16(         \
                                  af_[m_], bf_[n_], acc[m_][n_], 0, 0, 0);     \
    } } while (0)

#define VMC(n)  asm volatile("s_waitcnt vmcnt(" #n ")" ::: "memory")
#define LGKM0() asm volatile("s_waitcnt lgkmcnt(0)" ::: "memory")
#define SB()    __builtin_amdgcn_sched_barrier(0)
#define BAR()   __builtin_amdgcn_s_barrier()

    for (int mt = 0; mt * 128 < count; ++mt) {
        const unsigned char* asrc[4];
        #pragma unroll
        for (int i = 0; i < 4; ++i) {
            const int chunk = wv * 4 + i;
            const int row = chunk * 8 + (l >> 3);
            const int colbyte = ((l & 7) ^ (l >> 3)) << 4;
            int arow;
            if (MODE == 0) {
                int slot = off + mt * 128 + row;
                const int smax = off + count - 1;
                if (slot > smax) slot = smax;
                arow = slot_token[slot];
            } else {
                arow = off + mt * 128 + row;
            }
            asrc[i] = (const unsigned char*)A + (size_t)arow * 2048 + colbyte;
        }

        f32x4v acc[4][2];
        #pragma unroll
        for (int m = 0; m < 4; ++m)
            #pragma unroll
            for (int n = 0; n < 2; ++n)
                acc[m][n] = f32x4v{0.f, 0.f, 0.f, 0.f};

        float4 bvA[4], bvB[4];

        // ---- prologue: kt=0 into buf0 + bvA, kt=1 into buf1 + bvB ----
        DMA_A(0, 0); SB(); LOAD_B(bvA, 0); SB();
        DMA_A(1, 1); SB(); LOAD_B(bvB, 1); SB();
        VMC(8);                    // kt=0's A in LDS, bvA in regs; kt=1 in flight
        WRITE_B(bvA); LGKM0(); SB(); BAR();
        COMPUTE(0); BAR();

        // ---- steady: kt = 1..14, two per iteration ----
        #pragma unroll 1
        for (int p = 0; p < 7; ++p) {
            // kt = 2p+1: consume buf1 + bvB, prefetch kt+1 into buf0 + bvA
            DMA_A(0, 2 * p + 2); SB(); LOAD_B(bvA, 2 * p + 2); SB();
            VMC(8);
            WRITE_B(bvB); LGKM0(); SB(); BAR();
            COMPUTE(1); BAR();
            // kt = 2p+2: consume buf0 + bvA, prefetch kt+1 into buf1 + bvB
            DMA_A(1, 2 * p + 3); SB(); LOAD_B(bvB, 2 * p + 3); SB();
            VMC(8);
            WRITE_B(bvA); LGKM0(); SB(); BAR();
            COMPUTE(0); BAR();
        }

        // ---- tail: kt=15 (buf1 + bvB), nothing to prefetch ----
        VMC(0);
        WRITE_B(bvB); LGKM0(); SB(); BAR();
        COMPUTE(1);

        // ---- epilogue ----
        #pragma unroll
        for (int m = 0; m < 4; ++m) {
            #pragma unroll
            for (int n = 0; n < 2; ++n) {
                #pragma unroll
                for (int j = 0; j < 4; ++j) {
                    const int row  = wm * 64 + m * 16 + (l >> 4) * 4 + j;
                    const int coll = wn * 32 + n * 16 + (l & 15);
                    const int gn = nt * 64 + coll;
                    const int gm = mt * 128 + row;
                    if (MODE == 0) {
                        float v = acc[m][n][j] + Bias[(size_t)e * NPE + gn];
                        const float partner = __shfl_xor(v, 1, 64);
                        if (!(l & 1) && gm < count) {
                            const float g  = fminf(v, 7.0f);
                            const float lv = fminf(fmaxf(partner, -7.0f), 7.0f);
                            const float r  = g / (1.0f + expf(-1.702f * g)) * (lv + 1.0f);
                            act_out[(size_t)(off + gm) * 1024 + (gn >> 1)] = (__bf16)r;
                        }
                    } else {
                        if (gm < count) {
                            const int slot = off + gm;
                            const float v = acc[m][n][j] + Bias[(size_t)e * NPE + gn];
                            o_buf[(size_t)slot * 1024 + gn] = (__bf16)(v * slot_ew[slot]);
                        }
                    }
                }
            }
        }
        BAR();   // protect lds_a/lds_b reuse across mt iterations
    }
#undef DMA_A
#undef LOAD_B
#undef WRITE_B
#undef COMPUTE
#undef VMC
#undef LGKM0
#undef SB
#undef BAR
}

// ---------------- K6: out = x + sum_k o_buf[slot(t,k)] (obuf bf16) ----------------
__global__ __launch_bounds__(256) void k_combine(const float* __restrict__ x,
        const __bf16* __restrict__ o_buf, const int* __restrict__ tslot,
        float* __restrict__ out)
{
    const int t = blockIdx.x, tid = threadIdx.x;
    float4 r = ((const float4*)(x + (size_t)t * 1024))[tid];
    #pragma unroll
    for (int k = 0; k < 4; ++k) {
        const int s = tslot[t * 4 + k];
        const bf16x4 o = ((const bf16x4*)(o_buf + (size_t)s * 1024))[tid];
        r.x += (float)o[0]; r.y += (float)o[1];
        r.z += (float)o[2]; r.w += (float)o[3];
    }
    ((float4*)(out + (size_t)t * 1024))[tid] = r;
}

extern "C" void kernel_launch(void* const* d_in, const int* in_sizes, int n_in,
                              void* d_out, int out_size, void* d_ws, size_t ws_size,
                              hipStream_t stream)
{
    const float* x   = (const float*)d_in[0];
    const float* nsc = (const float*)d_in[1];
    const float* gw  = (const float*)d_in[2];
    const float* gb  = (const float*)d_in[3];
    const float* w1  = (const float*)d_in[4];
    const float* b1  = (const float*)d_in[5];
    const float* w2  = (const float*)d_in[6];
    const float* b2  = (const float*)d_in[7];
    float* out = (float*)d_out;
    (void)in_sizes; (void)n_in; (void)out_size; (void)ws_size;

    char* ws = (char*)d_ws;
    float*  t32   = (float*)(ws);                                  // 4 MiB
    __bf16* t16   = (__bf16*)(ws + (4u  << 20));                   // 2 MiB
    __bf16* act   = (__bf16*)(ws + (6u  << 20));                   // 8.4 MiB
    __bf16* obuf  = (__bf16*)(ws + (16u << 20));                   // 8.4 MiB
    int*    idx   = (int*)  (ws + (34u << 20));
    float*  ew    = (float*)(ws + (34u << 20) + 1 * 65536);
    int*    stok  = (int*)  (ws + (34u << 20) + 2 * 65536);
    float*  sew   = (float*)(ws + (34u << 20) + 3 * 65536);
    int*    tslot = (int*)  (ws + (34u << 20) + 4 * 65536);
    int*    eoff  = (int*)  (ws + (34u << 20) + 5 * 65536);

    k_rmsnorm<<<1024, 256, 0, stream>>>(x, nsc, t32, t16);
    k_gate   <<<1024, 256, 0, stream>>>(t32, gw, gb, idx, ew);
    k_bucket <<<   1, 256, 0, stream>>>(idx, ew, eoff, stok, sew, tslot);
    k_gemm<0><<<dim3(32, 64), 256, 0, stream>>>(w1, b1, t16, eoff, stok, sew, act, nullptr);
    k_gemm<1><<<dim3(16, 64), 256, 0, stream>>>(w2, b2, act, eoff, stok, sew, nullptr, obuf);
    k_combine<<<1024, 256, 0, stream>>>(x, obuf, tslot, out);
}